// Round 1
// baseline (549.065 us; speedup 1.0000x reference)
//
#include <hip/hip_runtime.h>

#define NB 1024   // batches
#define NN 4096   // rows per batch
#define P  16     // wdim

// ---------------------------------------------------------------------------
// Kernel 1: build M[b] = diag(rsqrt(rownorm2(inv(A)^T))) @ inv(A)^T
// A = tril(A_noise,-1) + diag(sqrt(chisq)). inv(A) is lower-tri (forward subst).
// Row j of M = scale_j * column j of inv(A), scale_j = rsqrt(||col_j||^2).
// One thread per batch; ~700 FMAs each. Negligible vs stage 2.
// ---------------------------------------------------------------------------
__global__ void build_M(const float* __restrict__ A_noise,
                        const float* __restrict__ chisq,
                        float* __restrict__ M) {
  const int b = blockIdx.x * blockDim.x + threadIdx.x;
  if (b >= NB) return;
  const float* An = A_noise + (size_t)b * P * P;
  float* Mb = M + (size_t)b * P * P;

  float rd[P];  // 1/diag = rsqrt(chisq)
#pragma unroll
  for (int i = 0; i < P; ++i) rd[i] = rsqrtf(chisq[b * P + i]);

  // strict lower triangle of A (120 values, fully unrolled into regs)
  float Al[P][P];
#pragma unroll
  for (int i = 1; i < P; ++i)
#pragma unroll
    for (int k = 0; k < i; ++k) Al[i][k] = An[i * P + k];

#pragma unroll
  for (int j = 0; j < P; ++j) {
    float col[P];  // column j of inv(A), rows j..15
    col[j] = rd[j];
    float n2 = col[j] * col[j];
#pragma unroll
    for (int i = j + 1; i < P; ++i) {
      float s = 0.f;
#pragma unroll
      for (int k = j; k < i; ++k) s += Al[i][k] * col[k];
      col[i] = -s * rd[i];
      n2 += col[i] * col[i];
    }
    const float sc = rsqrtf(n2);
#pragma unroll
    for (int i = 0; i < j; ++i) Mb[j * P + i] = 0.f;
#pragma unroll
    for (int i = j; i < P; ++i) Mb[j * P + i] = sc * col[i];
  }
}

// ---------------------------------------------------------------------------
// Kernel 2: w[b,n,:] = M[b] @ z[b,n,:]  — memory-bound (512 MB total traffic).
// 4 blocks per batch, 256 thr/block, 4 rows/thread (register-blocked so each
// LDS read of M amortizes over 4 rows; M reads are wave-uniform -> broadcast).
// ---------------------------------------------------------------------------
#define RPT 4
#define TPB 256

__global__ __launch_bounds__(TPB) void apply_M(const float* __restrict__ M,
                                               const float* __restrict__ z,
                                               float* __restrict__ w) {
  __shared__ float4 Ms[P * 4];  // 16 rows x 4 float4 segments = 1 KB
  const int b = blockIdx.x >> 2;
  const int chunk = blockIdx.x & 3;
  const int tid = threadIdx.x;
  if (tid < P * 4) Ms[tid] = ((const float4*)(M + (size_t)b * P * P))[tid];
  __syncthreads();

  const size_t row0 = (size_t)b * NN + (size_t)chunk * (NN / 4) + (size_t)tid * RPT;
  const float4* zin = (const float4*)z + row0 * 4;  // 4 float4 per 16-float row
  float4* wout = (float4*)w + row0 * 4;

  // load 4 rows of z (16 independent dwordx4 loads, issued before compute)
  float4 zr[RPT][4];
#pragma unroll
  for (int r = 0; r < RPT; ++r)
#pragma unroll
    for (int s = 0; s < 4; ++s) zr[r][s] = zin[r * 4 + s];

  float acc[RPT][P];
#pragma unroll
  for (int r = 0; r < RPT; ++r)
#pragma unroll
    for (int i = 0; i < P; ++i) acc[r][i] = 0.f;

#pragma unroll
  for (int s = 0; s < 4; ++s) {  // segment of the dot product (j = 4s..4s+3)
#pragma unroll
    for (int i = 0; i < P; ++i) {  // output element
      const float4 m = Ms[i * 4 + s];
#pragma unroll
      for (int r = 0; r < RPT; ++r) {
        acc[r][i] = fmaf(m.w, zr[r][s].w,
                    fmaf(m.z, zr[r][s].z,
                    fmaf(m.y, zr[r][s].y,
                    fmaf(m.x, zr[r][s].x, acc[r][i]))));
      }
    }
  }

#pragma unroll
  for (int r = 0; r < RPT; ++r)
#pragma unroll
    for (int s = 0; s < 4; ++s)
      wout[r * 4 + s] = make_float4(acc[r][s * 4 + 0], acc[r][s * 4 + 1],
                                    acc[r][s * 4 + 2], acc[r][s * 4 + 3]);
}

extern "C" void kernel_launch(void* const* d_in, const int* in_sizes, int n_in,
                              void* d_out, int out_size, void* d_ws, size_t ws_size,
                              hipStream_t stream) {
  const float* A_noise = (const float*)d_in[0];
  const float* chisq   = (const float*)d_in[1];
  const float* z       = (const float*)d_in[2];
  float* wv = (float*)d_out;
  float* Mw = (float*)d_ws;  // 1024*256*4 = 1 MB scratch for M

  build_M<<<NB / 256, 256, 0, stream>>>(A_noise, chisq, Mw);
  apply_M<<<NB * 4, TPB, 0, stream>>>(Mw, z, wv);
}

// Round 2
// 444.697 us; speedup vs baseline: 1.2347x; 1.2347x over previous
//
#include <hip/hip_runtime.h>

#define NB 1024   // batches
#define NN 4096   // rows per batch
#define P  16     // wdim

// ---------------------------------------------------------------------------
// Kernel 1: build M[b]: row j of M = scale_j * column j of inv(A),
// A = tril(A_noise,-1) + diag(sqrt(chisq)), scale_j = rsqrt(||col_j||^2).
// 16 threads per batch (one per column j). A staged in LDS; per-thread col
// lives in padded LDS (runtime loop bounds -> no register-array spills).
// Grid: 1024*16/256 = 64 blocks.
// ---------------------------------------------------------------------------
__global__ __launch_bounds__(256) void build_M(const float* __restrict__ A_noise,
                                               const float* __restrict__ chisq,
                                               float* __restrict__ M) {
  __shared__ float As[16][P][17];   // 16 batches x 16x16 A, +1 pad   (17.4 KB)
  __shared__ float colS[256][17];   // per-thread column workspace    (17.4 KB)

  const int tid = threadIdx.x;
  const int lb  = tid >> 4;         // local batch 0..15
  const int j   = tid & 15;         // column handled by this thread
  const int b   = blockIdx.x * 16 + lb;

  // cooperative stage of A: thread tid loads one 16-float row (flat row = tid)
  {
    const float* src = A_noise + (size_t)blockIdx.x * 16 * P * P + (size_t)tid * P;
    for (int v = 0; v < P; ++v) As[tid >> 4][tid & 15][v] = src[v];
  }
  __syncthreads();

  const float* cs = chisq + (size_t)b * P;
  float* col = colS[tid];

  const float cj = rsqrtf(cs[j]);   // B[j][j] = 1/d_j
  col[j] = cj;
  float n2 = cj * cj;
  for (int i = j + 1; i < P; ++i) {
    float s = 0.f;
    for (int k = j; k < i; ++k) s += As[lb][i][k] * col[k];
    const float ci = -s * rsqrtf(cs[i]);
    col[i] = ci;
    n2 += ci * ci;
  }
  const float sc = rsqrtf(n2);

  float* Mb = M + (size_t)b * P * P + (size_t)j * P;  // row j of M[b]
  for (int i = 0; i < j; ++i) Mb[i] = 0.f;
  for (int i = j; i < P; ++i) Mb[i] = sc * col[i];
}

// ---------------------------------------------------------------------------
// Kernel 2: w[b,n,:] = M[b] @ z[b,n,:]  — memory-bound, 512 MB ideal traffic.
// One float4 SEGMENT per lane, lane-consecutive -> every global load/store
// instruction covers a contiguous 1 KB full-line span (no partial-line
// amplification). Each lane owns output quarter q = tid&3 of its row and
// pre-loads M rows 4q..4q+3 into registers; the quad's other z-segments are
// gathered with __shfl within the aligned 4-lane group.
// ---------------------------------------------------------------------------
#define TPB 256
#define RPT 8                                     // float4 segments per thread
#define SEGB (NN * 4)                             // segments per batch = 16384
#define BPB  (SEGB / (TPB * RPT))                 // blocks per batch = 8

__global__ __launch_bounds__(TPB) void apply_M(const float* __restrict__ M,
                                               const float* __restrict__ z,
                                               float* __restrict__ w) {
  const int b     = blockIdx.x >> 3;
  const int chunk = blockIdx.x & 7;
  const int tid   = threadIdx.x;
  const int q     = tid & 3;                      // quarter owned by this lane
  const int quad0 = tid & ~3;                     // first lane of my quad

  // M rows 4q..4q+3 (this lane's 4 outputs), 16 float4 = 64 VGPRs.
  const float4* Mf4 = (const float4*)(M + (size_t)b * P * P);
  float4 Mr[4][4];
#pragma unroll
  for (int c = 0; c < 4; ++c)
#pragma unroll
    for (int s = 0; s < 4; ++s) Mr[c][s] = Mf4[(4 * q + c) * 4 + s];

  const size_t segbase = (size_t)b * SEGB + (size_t)chunk * (TPB * RPT) + tid;
  const float4* zf4 = (const float4*)z;
  float4* wf4 = (float4*)w;

  // coalesced loads: lane-consecutive float4s, RPT independent, issued up front
  float4 zv[RPT];
#pragma unroll
  for (int k = 0; k < RPT; ++k) zv[k] = zf4[segbase + (size_t)k * TPB];

#pragma unroll
  for (int k = 0; k < RPT; ++k) {
    // gather the full 16-float z row across the 4-lane quad
    float4 row[4];
#pragma unroll
    for (int d = 0; d < 4; ++d) {
      row[d].x = __shfl(zv[k].x, quad0 + d, 64);
      row[d].y = __shfl(zv[k].y, quad0 + d, 64);
      row[d].z = __shfl(zv[k].z, quad0 + d, 64);
      row[d].w = __shfl(zv[k].w, quad0 + d, 64);
    }
    // out[c] = M[4q+c][:] . row[:]
    float out[4];
#pragma unroll
    for (int c = 0; c < 4; ++c) {
      float acc = 0.f;
#pragma unroll
      for (int s = 0; s < 4; ++s) {
        acc = fmaf(Mr[c][s].x, row[s].x, acc);
        acc = fmaf(Mr[c][s].y, row[s].y, acc);
        acc = fmaf(Mr[c][s].z, row[s].z, acc);
        acc = fmaf(Mr[c][s].w, row[s].w, acc);
      }
      out[c] = acc;
    }
    wf4[segbase + (size_t)k * TPB] = make_float4(out[0], out[1], out[2], out[3]);
  }
}

extern "C" void kernel_launch(void* const* d_in, const int* in_sizes, int n_in,
                              void* d_out, int out_size, void* d_ws, size_t ws_size,
                              hipStream_t stream) {
  const float* A_noise = (const float*)d_in[0];
  const float* chisq   = (const float*)d_in[1];
  const float* z       = (const float*)d_in[2];
  float* wv = (float*)d_out;
  float* Mw = (float*)d_ws;  // 1 MB scratch for M

  build_M<<<NB / 16, 256, 0, stream>>>(A_noise, chisq, Mw);
  apply_M<<<NB * BPB, TPB, 0, stream>>>(Mw, z, wv);
}